// Round 2
// baseline (362.690 us; speedup 1.0000x reference)
//
#include <hip/hip_runtime.h>

// ---------------------------------------------------------------------------
// GridMERA 16x16 forward.
// Inputs (d_in order): inputs[128,16,16,1], e1[16^4,4^4], e2[4^8],
//   iso1_0[16,16,16,4,4], iso1_1[16,16,4,16,4], iso1_2[16,4,16,16,4],
//   iso1_3[4,16,16,16,4], iso2[4,4,4,4,10], bias[10]
// Output: [128,10] fp32.
//
// Workspace layout (bytes):
//   xv    @ 0        : 128*256*4   = 131072   (patches, [B][k][d])
//   tt    @ 131072   : 4*128*16*4  = 32768    (iso1 outputs, [iso][B][m*4+o])
//   M2    @ 163840   : 256*10*4    = 10240    (e2·iso2, [abcd][C])
//   vpart @ 262144   : 64*128*256*4 = 8388608 (split-K partials of v)
// ---------------------------------------------------------------------------

#define KC 64  // number of K-chunks in the big GEMM (K = 65536, chunk = 1024)

// K1: extract patches xv[b][k][d] = in[b][(k>>2)*4+(d>>2)][(k&3)*4+(d&3)]
__global__ void k1_xv(const float* __restrict__ in, float* __restrict__ xv) {
    int b = blockIdx.x, t = threadIdx.x;       // t = k*16 + d
    int k = t >> 4, d = t & 15;
    int row = (k >> 2) * 4 + (d >> 2);
    int col = (k & 3) * 4 + (d & 3);
    xv[b * 256 + t] = in[b * 256 + row * 16 + col];
}

// K2: t_x[B][m][o] = sum_{ijk} iso_x[...] * pX[i]*pY[j]*pZ[k]
// grid 64 = iso(4) x m(4) x o(4); block 128 (thread = batch)
__global__ void k2_iso(const float* __restrict__ i0, const float* __restrict__ i1,
                       const float* __restrict__ i2, const float* __restrict__ i3,
                       const float* __restrict__ xv, float* __restrict__ tt) {
    int blk = blockIdx.x;
    int iso = blk >> 4, mo = blk & 15, m = mo >> 2, o = mo & 3;
    int t = threadIdx.x;  // batch

    // per-iso tables (iso is block-uniform)
    const int pid0[4] = {0, 2, 8, 11};
    const int pid1[4] = {1, 3, 12, 14};
    const int pid2[4] = {4, 7, 13, 15};
    const int siA[4] = {4096, 4096, 4096, 1024};
    const int sjA[4] = {256, 256, 64, 64};
    const int skA[4] = {16, 4, 4, 4};
    const int smA[4] = {4, 64, 1024, 16384};

    const float* iso_p = (iso == 0) ? i0 : (iso == 1) ? i1 : (iso == 2) ? i2 : i3;
    int si = siA[iso], sj = sjA[iso], sk = skA[iso];
    int base = m * smA[iso] + o;

    __shared__ float pX[128 * 16], pY[128 * 16], pZ[128 * 16];
    __shared__ float col[128];

    for (int s = t; s < 2048; s += 128) {
        int b = s >> 4, d = s & 15;
        pX[s] = xv[b * 256 + pid0[iso] * 16 + d];
        pY[s] = xv[b * 256 + pid1[iso] * 16 + d];
        pZ[s] = xv[b * 256 + pid2[iso] * 16 + d];
    }

    float acc = 0.f;
    for (int chunk = 0; chunk < 32; ++chunk) {
        __syncthreads();
        int flat = chunk * 128 + t;
        int i = flat >> 8, j = (flat >> 4) & 15, k = flat & 15;
        col[t] = iso_p[base + i * si + j * sj + k * sk];
        __syncthreads();
        for (int n = 0; n < 128; ++n) {
            int f2 = chunk * 128 + n;
            int ii = f2 >> 8, jj = (f2 >> 4) & 15, kk = f2 & 15;
            acc += col[n] * pX[t * 16 + ii] * pY[t * 16 + jj] * pZ[t * 16 + kk];
        }
    }
    tt[iso * 2048 + t * 16 + mo] = acc;
}

// K3: M2[q][C] = sum_r e2[q*256+r] * iso2[r*10+C]   (q = abcd, 256; C = 10)
// grid 10, block 256 -> flat 0..2559
__global__ void k3_m2(const float* __restrict__ e2, const float* __restrict__ iso2,
                      float* __restrict__ M2) {
    __shared__ float is2[2560];
    int t = threadIdx.x;
    for (int s = t; s < 2560; s += 256) is2[s] = iso2[s];
    __syncthreads();
    int flat = blockIdx.x * 256 + t;
    int q = flat / 10, C = flat % 10;
    float acc = 0.f;
    for (int r = 0; r < 256; ++r) acc += e2[q * 256 + r] * is2[r * 10 + C];
    M2[q * 10 + C] = acc;
}

// K4: split-K GEMM partials.
//   vpart[kc][b][col] = sum_{k in chunk kc, col in colgroup}
//       p5[a]*p6[bb]*p9[c]*p10[d] * e1[k*256+col]
// grid (KC, 4); block 256. thread: cg = tid&15 (4 cols), bq = tid>>4 (8 batches)
__global__ void __launch_bounds__(256) k4_gemm(const float* __restrict__ e1,
                                               const float* __restrict__ xv,
                                               float* __restrict__ vpart) {
    __shared__ float p5l[2048], p6l[2048], p9l[2048], p10l[2048];
    int tid = threadIdx.x;
    for (int s = tid; s < 2048; s += 256) {
        int b = s >> 4, d = s & 15;
        p5l[s]  = xv[b * 256 + 5 * 16 + d];
        p6l[s]  = xv[b * 256 + 6 * 16 + d];
        p9l[s]  = xv[b * 256 + 9 * 16 + d];
        p10l[s] = xv[b * 256 + 10 * 16 + d];
    }
    __syncthreads();

    int cg = tid & 15;   // column group: 4 consecutive floats
    int bq = tid >> 4;   // batch group: 8 batches
    int kc = blockIdx.x;
    int colbase = blockIdx.y * 64 + cg * 4;

    float4 acc[8];
#pragma unroll
    for (int i = 0; i < 8; ++i) acc[i] = make_float4(0.f, 0.f, 0.f, 0.f);

    const float* e1base = e1 + (size_t)(kc * 1024) * 256 + colbase;

    for (int abi = 0; abi < 4; ++abi) {
        int ab = kc * 4 + abi;
        int a = ab >> 4, bb = ab & 15;
        float wab[8];
#pragma unroll
        for (int i = 0; i < 8; ++i) {
            int b = bq * 8 + i;
            wab[i] = p5l[b * 16 + a] * p6l[b * 16 + bb];
        }
        for (int c = 0; c < 16; ++c) {
            float pabc[8];
#pragma unroll
            for (int i = 0; i < 8; ++i) pabc[i] = wab[i] * p9l[(bq * 8 + i) * 16 + c];
            const float* ep = e1base + (size_t)((abi * 16 + c) * 16) * 256;
#pragma unroll
            for (int d = 0; d < 16; ++d) {
                float4 ev = *(const float4*)(ep + (size_t)d * 256);
#pragma unroll
                for (int i = 0; i < 8; ++i) {
                    float w = pabc[i] * p10l[(bq * 8 + i) * 16 + d];
                    acc[i].x += w * ev.x;
                    acc[i].y += w * ev.y;
                    acc[i].z += w * ev.z;
                    acc[i].w += w * ev.w;
                }
            }
        }
    }
#pragma unroll
    for (int i = 0; i < 8; ++i) {
        int b = bq * 8 + i;
        *(float4*)&vpart[((size_t)kc * 128 + b) * 256 + colbase] = acc[i];
    }
}

// K5: reduce split-K partials -> v[256]; then per-batch tail contraction.
// grid 128 (batch), block 64.
__global__ void k5_final(const float* __restrict__ vpart, const float* __restrict__ tt,
                         const float* __restrict__ M2, const float* __restrict__ bias,
                         float* __restrict__ out) {
    __shared__ float v[256], A[256], Bb[256];
    __shared__ float t0[16], t1[16], t2[16], t3[16];
    int b = blockIdx.x, t = threadIdx.x;

    float4 s = make_float4(0.f, 0.f, 0.f, 0.f);
    for (int kc = 0; kc < KC; ++kc) {
        float4 pv = *(const float4*)&vpart[((size_t)kc * 128 + b) * 256 + t * 4];
        s.x += pv.x; s.y += pv.y; s.z += pv.z; s.w += pv.w;
    }
    *(float4*)&v[t * 4] = s;
    if (t < 16) {
        t0[t] = tt[0 * 2048 + b * 16 + t];
        t1[t] = tt[1 * 2048 + b * 16 + t];
        t2[t] = tt[2 * 2048 + b * 16 + t];
        t3[t] = tt[3 * 2048 + b * 16 + t];
    }
    __syncthreads();

    // stage1: A[a*64+fgh] = sum_e t0[e*4+a] * v[e*64+fgh]
    for (int q = 0; q < 4; ++q) {
        int idx = t * 4 + q;
        int a = idx >> 6, fgh = idx & 63;
        float acc = 0.f;
        for (int e = 0; e < 4; ++e) acc += t0[e * 4 + a] * v[e * 64 + fgh];
        A[idx] = acc;
    }
    __syncthreads();
    // stage2: Bb[a*64+bb*16+gh] = sum_f t1[f*4+bb] * A[a*64+f*16+gh]
    for (int q = 0; q < 4; ++q) {
        int idx = t * 4 + q;
        int a = idx >> 6, bb = (idx >> 4) & 3, gh = idx & 15;
        float acc = 0.f;
        for (int f = 0; f < 4; ++f) acc += t1[f * 4 + bb] * A[a * 64 + f * 16 + gh];
        Bb[idx] = acc;
    }
    __syncthreads();
    // stage3: A[ab*16+c*4+h] = sum_g t2[g*4+c] * Bb[ab*16+g*4+h]
    for (int q = 0; q < 4; ++q) {
        int idx = t * 4 + q;
        int ab = idx >> 4, c = (idx >> 2) & 3, h = idx & 3;
        float acc = 0.f;
        for (int g = 0; g < 4; ++g) acc += t2[g * 4 + c] * Bb[ab * 16 + g * 4 + h];
        A[idx] = acc;
    }
    __syncthreads();
    // stage4: w[abc*4+dd] = sum_h t3[h*4+dd] * A[abc*4+h]
    for (int q = 0; q < 4; ++q) {
        int idx = t * 4 + q;
        int abc = idx >> 2, dd = idx & 3;
        float acc = 0.f;
        for (int h = 0; h < 4; ++h) acc += t3[h * 4 + dd] * A[abc * 4 + h];
        Bb[idx] = acc;
    }
    __syncthreads();
    // out[C] = bias[C] + sum_q w[q] * M2[q*10+C]
    if (t < 10) {
        float acc = bias[t];
        for (int q = 0; q < 256; ++q) acc += Bb[q] * M2[q * 10 + t];
        out[b * 10 + t] = acc;
    }
}

extern "C" void kernel_launch(void* const* d_in, const int* in_sizes, int n_in,
                              void* d_out, int out_size, void* d_ws, size_t ws_size,
                              hipStream_t stream) {
    const float* in    = (const float*)d_in[0];
    const float* e1    = (const float*)d_in[1];
    const float* e2    = (const float*)d_in[2];
    const float* iso10 = (const float*)d_in[3];
    const float* iso11 = (const float*)d_in[4];
    const float* iso12 = (const float*)d_in[5];
    const float* iso13 = (const float*)d_in[6];
    const float* iso2  = (const float*)d_in[7];
    const float* bias  = (const float*)d_in[8];
    float* out = (float*)d_out;

    char* ws = (char*)d_ws;
    float* xv    = (float*)(ws + 0);
    float* tt    = (float*)(ws + 131072);
    float* M2    = (float*)(ws + 163840);
    float* vpart = (float*)(ws + 262144);

    hipLaunchKernelGGL(k1_xv, dim3(128), dim3(256), 0, stream, in, xv);
    hipLaunchKernelGGL(k2_iso, dim3(64), dim3(128), 0, stream,
                       iso10, iso11, iso12, iso13, xv, tt);
    hipLaunchKernelGGL(k3_m2, dim3(10), dim3(256), 0, stream, e2, iso2, M2);
    hipLaunchKernelGGL(k4_gemm, dim3(KC, 4), dim3(256), 0, stream, e1, xv, vpart);
    hipLaunchKernelGGL(k5_final, dim3(128), dim3(64), 0, stream,
                       vpart, tt, M2, bias, out);
}

// Round 3
// 298.575 us; speedup vs baseline: 1.2147x; 1.2147x over previous
//
#include <hip/hip_runtime.h>

// ---------------------------------------------------------------------------
// GridMERA 16x16 forward.  fp32 throughout.
// Inputs (d_in order): inputs[128,16,16,1], e1[16^4,4^4], e2[4^8],
//   iso1_0[16,16,16,4,4], iso1_1[16,16,4,16,4], iso1_2[16,4,16,16,4],
//   iso1_3[4,16,16,16,4], iso2[4,4,4,4,10], bias[10]
// Output: [128,10] fp32.
//
// Workspace layout (bytes):
//   xv    @ 0        : 128*256*4   = 131072   (patches, [B][k][d])
//   tt    @ 131072   : 4*128*16*4  = 32768    (iso1 outputs, [iso][B][m*4+o])
//   M2    @ 163840   : 256*10*4    = 10240    (e2·iso2, [abcd][C])
//   vpart @ 262144   : 64*128*256*4 = 8388608 (split-K partials of v)
// ---------------------------------------------------------------------------

#define KC 64  // K-chunks in the big GEMM (K = 65536, chunk = 1024 = 4 ab-values)

// K1: extract patches xv[b][k][d] = in[b][(k>>2)*4+(d>>2)][(k&3)*4+(d&3)]
__global__ void k1_xv(const float* __restrict__ in, float* __restrict__ xv) {
    int b = blockIdx.x, t = threadIdx.x;       // t = k*16 + d
    int k = t >> 4, d = t & 15;
    int row = (k >> 2) * 4 + (d >> 2);
    int col = (k & 3) * 4 + (d & 3);
    xv[b * 256 + t] = in[b * 256 + row * 16 + col];
}

// K2 v2: one block per (batch, iso).  thread t = (i = t>>4, j = t&15), loops k.
// acc[mo] in registers; padded-LDS transpose reduce (stride 257 -> 2-way max).
__global__ void __launch_bounds__(256) k2_iso(
        const float* __restrict__ i0, const float* __restrict__ i1,
        const float* __restrict__ i2, const float* __restrict__ i3,
        const float* __restrict__ xv, float* __restrict__ tt) {
    int b = blockIdx.x, iso = blockIdx.y;
    int t = threadIdx.x;

    const int pid0[4] = {0, 2, 8, 11};
    const int pid1[4] = {1, 3, 12, 14};
    const int pid2[4] = {4, 7, 13, 15};
    const int siA[4] = {4096, 4096, 4096, 1024};
    const int sjA[4] = {256, 256, 64, 64};
    const int skA[4] = {16, 4, 4, 4};
    const int smA[4] = {4, 64, 1024, 16384};

    const float* iso_p = (iso == 0) ? i0 : (iso == 1) ? i1 : (iso == 2) ? i2 : i3;

    __shared__ float pX[16], pY[16], pZ[16];
    if (t < 16)      pX[t]      = xv[b * 256 + pid0[iso] * 16 + t];
    else if (t < 32) pY[t - 16] = xv[b * 256 + pid1[iso] * 16 + (t - 16)];
    else if (t < 48) pZ[t - 32] = xv[b * 256 + pid2[iso] * 16 + (t - 32)];
    __syncthreads();

    int i = t >> 4, j = t & 15;
    float pxy = pX[i] * pY[j];
    int sk = skA[iso], sm = smA[iso];
    const float* basep = iso_p + i * siA[iso] + j * sjA[iso];

    float acc[16];
#pragma unroll
    for (int mo = 0; mo < 16; ++mo) acc[mo] = 0.f;

    for (int k = 0; k < 16; ++k) {
        float w = pxy * pZ[k];
        const float* kp = basep + k * sk;
#pragma unroll
        for (int m = 0; m < 4; ++m) {
            float4 v = *(const float4*)(kp + m * sm);
            acc[m * 4 + 0] += w * v.x;
            acc[m * 4 + 1] += w * v.y;
            acc[m * 4 + 2] += w * v.z;
            acc[m * 4 + 3] += w * v.w;
        }
    }

    // transpose reduce: red[mo][t], stride 257 (257%32==1 -> 2-way max).
    __shared__ float red[16 * 257];
    __shared__ float part[256];
#pragma unroll
    for (int mo = 0; mo < 16; ++mo) red[mo * 257 + t] = acc[mo];
    __syncthreads();
    int mo = t & 15, seg = t >> 4;
    float s = 0.f;
#pragma unroll
    for (int u = 0; u < 16; ++u) s += red[mo * 257 + seg * 16 + u];
    part[mo * 16 + seg] = s;
    __syncthreads();
    if (t < 16) {
        float o = 0.f;
#pragma unroll
        for (int s2 = 0; s2 < 16; ++s2) o += part[t * 16 + s2];
        tt[iso * 2048 + b * 16 + t] = o;
    }
}

// K3: M2[q][C] = sum_r e2[q*256+r] * iso2[r*10+C]   (q = abcd, 256; C = 10)
__global__ void k3_m2(const float* __restrict__ e2, const float* __restrict__ iso2,
                      float* __restrict__ M2) {
    __shared__ float is2[2560];
    int t = threadIdx.x;
    for (int s = t; s < 2560; s += 256) is2[s] = iso2[s];
    __syncthreads();
    int flat = blockIdx.x * 256 + t;
    int q = flat / 10, C = flat % 10;
    float acc = 0.f;
    for (int r = 0; r < 256; ++r) acc += e2[q * 256 + r] * is2[r * 10 + C];
    M2[q * 10 + C] = acc;
}

// K4 v2: split-K GEMM partials, p-values hoisted to registers, no LDS in loop.
// grid (KC, 8); block 256: cg = tid&7 (4 cols), bq = tid>>3 (4 batches).
// 2 blocks/CU.  vpart[kc][b][col] layout unchanged.
__global__ void __launch_bounds__(256, 2) k4_gemm(const float* __restrict__ e1,
                                                  const float* __restrict__ xv,
                                                  float* __restrict__ vpart) {
    __shared__ float wabS[128 * 5];            // [b][abi], stride 5 (pad)
    __shared__ float p9S[128 * 17], p10S[128 * 17];  // [b][c], stride 17 (pad)
    int tid = threadIdx.x;
    int kc = blockIdx.x;

    // stage wab = p5[a]*p6[bb] for this block's 4 ab values
    for (int s = tid; s < 512; s += 256) {
        int b = s >> 2, abi = s & 3;
        int ab = kc * 4 + abi, a = ab >> 4, bb = ab & 15;
        wabS[b * 5 + abi] = xv[b * 256 + 5 * 16 + a] * xv[b * 256 + 6 * 16 + bb];
    }
    // stage p9, p10 (all 128 batches x 16)
    for (int s = tid; s < 2048; s += 256) {
        int b = s >> 4, c = s & 15;
        p9S[b * 17 + c]  = xv[b * 256 + 9 * 16 + c];
        p10S[b * 17 + c] = xv[b * 256 + 10 * 16 + c];
    }
    __syncthreads();

    int cg = tid & 7;    // 4 cols each
    int bq = tid >> 3;   // 4 batches each
    int colbase = blockIdx.y * 32 + cg * 4;

    // hoist all p-values to registers (static indexing only)
    float wab[4][4], p9r[4][16], p10r[4][16];
#pragma unroll
    for (int i = 0; i < 4; ++i) {
        int b = bq * 4 + i;
#pragma unroll
        for (int abi = 0; abi < 4; ++abi) wab[i][abi] = wabS[b * 5 + abi];
#pragma unroll
        for (int c = 0; c < 16; ++c) {
            p9r[i][c]  = p9S[b * 17 + c];
            p10r[i][c] = p10S[b * 17 + c];
        }
    }

    float4 acc[4];
#pragma unroll
    for (int i = 0; i < 4; ++i) acc[i] = make_float4(0.f, 0.f, 0.f, 0.f);

    const float* e1p = e1 + (size_t)(kc * 1024) * 256 + colbase;

#pragma unroll
    for (int abi = 0; abi < 4; ++abi) {
        for (int c = 0; c < 16; ++c) {
            float pabc[4];
#pragma unroll
            for (int i = 0; i < 4; ++i) pabc[i] = wab[i][abi] * p9r[i][c];
            const float* ep = e1p + (size_t)((abi * 16 + c) * 16) * 256;
#pragma unroll
            for (int d = 0; d < 16; ++d) {
                float4 ev = *(const float4*)(ep + (size_t)d * 256);
#pragma unroll
                for (int i = 0; i < 4; ++i) {
                    float w = pabc[i] * p10r[i][d];
                    acc[i].x += w * ev.x;
                    acc[i].y += w * ev.y;
                    acc[i].z += w * ev.z;
                    acc[i].w += w * ev.w;
                }
            }
        }
    }
#pragma unroll
    for (int i = 0; i < 4; ++i) {
        int b = bq * 4 + i;
        *(float4*)&vpart[((size_t)kc * 128 + b) * 256 + colbase] = acc[i];
    }
}

// K5: reduce split-K partials -> v[256]; then per-batch tail contraction.
__global__ void k5_final(const float* __restrict__ vpart, const float* __restrict__ tt,
                         const float* __restrict__ M2, const float* __restrict__ bias,
                         float* __restrict__ out) {
    __shared__ float v[256], A[256], Bb[256];
    __shared__ float t0[16], t1[16], t2[16], t3[16];
    int b = blockIdx.x, t = threadIdx.x;

    float4 s = make_float4(0.f, 0.f, 0.f, 0.f);
    for (int kc = 0; kc < KC; ++kc) {
        float4 pv = *(const float4*)&vpart[((size_t)kc * 128 + b) * 256 + t * 4];
        s.x += pv.x; s.y += pv.y; s.z += pv.z; s.w += pv.w;
    }
    *(float4*)&v[t * 4] = s;
    if (t < 16) {
        t0[t] = tt[0 * 2048 + b * 16 + t];
        t1[t] = tt[1 * 2048 + b * 16 + t];
        t2[t] = tt[2 * 2048 + b * 16 + t];
        t3[t] = tt[3 * 2048 + b * 16 + t];
    }
    __syncthreads();

    // stage1: A[a*64+fgh] = sum_e t0[e*4+a] * v[e*64+fgh]
    for (int q = 0; q < 4; ++q) {
        int idx = t * 4 + q;
        int a = idx >> 6, fgh = idx & 63;
        float acc = 0.f;
        for (int e = 0; e < 4; ++e) acc += t0[e * 4 + a] * v[e * 64 + fgh];
        A[idx] = acc;
    }
    __syncthreads();
    // stage2: Bb[a*64+bb*16+gh] = sum_f t1[f*4+bb] * A[a*64+f*16+gh]
    for (int q = 0; q < 4; ++q) {
        int idx = t * 4 + q;
        int a = idx >> 6, bb = (idx >> 4) & 3, gh = idx & 15;
        float acc = 0.f;
        for (int f = 0; f < 4; ++f) acc += t1[f * 4 + bb] * A[a * 64 + f * 16 + gh];
        Bb[idx] = acc;
    }
    __syncthreads();
    // stage3: A[ab*16+c*4+h] = sum_g t2[g*4+c] * Bb[ab*16+g*4+h]
    for (int q = 0; q < 4; ++q) {
        int idx = t * 4 + q;
        int ab = idx >> 4, c = (idx >> 2) & 3, h = idx & 3;
        float acc = 0.f;
        for (int g = 0; g < 4; ++g) acc += t2[g * 4 + c] * Bb[ab * 16 + g * 4 + h];
        A[idx] = acc;
    }
    __syncthreads();
    // stage4: w[abc*4+dd] = sum_h t3[h*4+dd] * A[abc*4+h]
    for (int q = 0; q < 4; ++q) {
        int idx = t * 4 + q;
        int abc = idx >> 2, dd = idx & 3;
        float acc = 0.f;
        for (int h = 0; h < 4; ++h) acc += t3[h * 4 + dd] * A[abc * 4 + h];
        Bb[idx] = acc;
    }
    __syncthreads();
    // out[C] = bias[C] + sum_q w[q] * M2[q*10+C]
    if (t < 10) {
        float acc = bias[t];
        for (int q = 0; q < 256; ++q) acc += Bb[q] * M2[q * 10 + t];
        out[b * 10 + t] = acc;
    }
}

extern "C" void kernel_launch(void* const* d_in, const int* in_sizes, int n_in,
                              void* d_out, int out_size, void* d_ws, size_t ws_size,
                              hipStream_t stream) {
    const float* in    = (const float*)d_in[0];
    const float* e1    = (const float*)d_in[1];
    const float* e2    = (const float*)d_in[2];
    const float* iso10 = (const float*)d_in[3];
    const float* iso11 = (const float*)d_in[4];
    const float* iso12 = (const float*)d_in[5];
    const float* iso13 = (const float*)d_in[6];
    const float* iso2  = (const float*)d_in[7];
    const float* bias  = (const float*)d_in[8];
    float* out = (float*)d_out;

    char* ws = (char*)d_ws;
    float* xv    = (float*)(ws + 0);
    float* tt    = (float*)(ws + 131072);
    float* M2    = (float*)(ws + 163840);
    float* vpart = (float*)(ws + 262144);

    hipLaunchKernelGGL(k1_xv, dim3(128), dim3(256), 0, stream, in, xv);
    hipLaunchKernelGGL(k2_iso, dim3(128, 4), dim3(256), 0, stream,
                       iso10, iso11, iso12, iso13, xv, tt);
    hipLaunchKernelGGL(k3_m2, dim3(10), dim3(256), 0, stream, e2, iso2, M2);
    hipLaunchKernelGGL(k4_gemm, dim3(KC, 8), dim3(256), 0, stream, e1, xv, vpart);
    hipLaunchKernelGGL(k5_final, dim3(128), dim3(64), 0, stream,
                       vpart, tt, M2, bias, out);
}

// Round 8
// 190.843 us; speedup vs baseline: 1.9005x; 1.5645x over previous
//
#include <hip/hip_runtime.h>

// ---------------------------------------------------------------------------
// GridMERA 16x16 forward.
// Inputs (d_in order): inputs[128,16,16,1], e1[16^4,4^4], e2[4^8],
//   iso1_0[16,16,16,4,4], iso1_1[16,16,4,16,4], iso1_2[16,4,16,16,4],
//   iso1_3[4,16,16,16,4], iso2[4,4,4,4,10], bias[10]
// Output: [128,10] fp32.
//
// Workspace layout (bytes):
//   xv    @ 0        : 128*256*4   = 131072   (patches, [B][k][d])
//   tt    @ 131072   : 4*128*16*4  = 32768    (iso1 outputs, [iso][B][m*4+o])
//   M2    @ 163840   : 256*10*4    = 10240    (e2·iso2, [abcd][C])
//   vpart @ 262144   : 64*128*256*4 = 8388608 (split-K partials of v)
// ---------------------------------------------------------------------------

#define KC 64  // K-chunks in the big GEMM (K = 65536, chunk = 1024 = 4 ab-values)

typedef __attribute__((ext_vector_type(8))) short bf16x8;
typedef __attribute__((ext_vector_type(4))) float f32x4;

// truncation split: x = hi + rem exactly; lo = trunc_bf16(rem).
// dropped tail <= 2^-16 |x|  -> plenty under the 2% absmax threshold.
__device__ __forceinline__ void splitf(float x, short& h, short& l) {
    unsigned u = __builtin_bit_cast(unsigned, x);
    h = (short)(u >> 16);
    float hf = __builtin_bit_cast(float, u & 0xFFFF0000u);
    float rem = x - hf;
    l = (short)(__builtin_bit_cast(unsigned, rem) >> 16);
}

// K1: extract patches xv[b][k][d] = in[b][(k>>2)*4+(d>>2)][(k&3)*4+(d&3)]
__global__ void k1_xv(const float* __restrict__ in, float* __restrict__ xv) {
    int b = blockIdx.x, t = threadIdx.x;       // t = k*16 + d
    int k = t >> 4, d = t & 15;
    int row = (k >> 2) * 4 + (d >> 2);
    int col = (k & 3) * 4 + (d & 3);
    xv[b * 256 + t] = in[b * 256 + row * 16 + col];
}

// K2: one block per (batch, iso).  thread t = (i = t>>4, j = t&15), loops k.
__global__ void __launch_bounds__(256) k2_iso(
        const float* __restrict__ i0, const float* __restrict__ i1,
        const float* __restrict__ i2, const float* __restrict__ i3,
        const float* __restrict__ xv, float* __restrict__ tt) {
    int b = blockIdx.x, iso = blockIdx.y;
    int t = threadIdx.x;

    const int pid0[4] = {0, 2, 8, 11};
    const int pid1[4] = {1, 3, 12, 14};
    const int pid2[4] = {4, 7, 13, 15};
    const int siA[4] = {4096, 4096, 4096, 1024};
    const int sjA[4] = {256, 256, 64, 64};
    const int skA[4] = {16, 4, 4, 4};
    const int smA[4] = {4, 64, 1024, 16384};

    const float* iso_p = (iso == 0) ? i0 : (iso == 1) ? i1 : (iso == 2) ? i2 : i3;

    __shared__ float pX[16], pY[16], pZ[16];
    if (t < 16)      pX[t]      = xv[b * 256 + pid0[iso] * 16 + t];
    else if (t < 32) pY[t - 16] = xv[b * 256 + pid1[iso] * 16 + (t - 16)];
    else if (t < 48) pZ[t - 32] = xv[b * 256 + pid2[iso] * 16 + (t - 32)];
    __syncthreads();

    int i = t >> 4, j = t & 15;
    float pxy = pX[i] * pY[j];
    int sk = skA[iso], sm = smA[iso];
    const float* basep = iso_p + i * siA[iso] + j * sjA[iso];

    float acc[16];
#pragma unroll
    for (int mo = 0; mo < 16; ++mo) acc[mo] = 0.f;

    for (int k = 0; k < 16; ++k) {
        float w = pxy * pZ[k];
        const float* kp = basep + k * sk;
#pragma unroll
        for (int m = 0; m < 4; ++m) {
            float4 v = *(const float4*)(kp + m * sm);
            acc[m * 4 + 0] += w * v.x;
            acc[m * 4 + 1] += w * v.y;
            acc[m * 4 + 2] += w * v.z;
            acc[m * 4 + 3] += w * v.w;
        }
    }

    __shared__ float red[16 * 257];
    __shared__ float part[256];
#pragma unroll
    for (int mo = 0; mo < 16; ++mo) red[mo * 257 + t] = acc[mo];
    __syncthreads();
    int mo = t & 15, seg = t >> 4;
    float s = 0.f;
#pragma unroll
    for (int u = 0; u < 16; ++u) s += red[mo * 257 + seg * 16 + u];
    part[mo * 16 + seg] = s;
    __syncthreads();
    if (t < 16) {
        float o = 0.f;
#pragma unroll
        for (int s2 = 0; s2 < 16; ++s2) o += part[t * 16 + s2];
        tt[iso * 2048 + b * 16 + t] = o;
    }
}

// K3: M2[q][C] = sum_r e2[q*256+r] * iso2[r*10+C]
__global__ void k3_m2(const float* __restrict__ e2, const float* __restrict__ iso2,
                      float* __restrict__ M2) {
    __shared__ float is2[2560];
    int t = threadIdx.x;
    for (int s = t; s < 2560; s += 256) is2[s] = iso2[s];
    __syncthreads();
    int flat = blockIdx.x * 256 + t;
    int q = flat / 10, C = flat % 10;
    float acc = 0.f;
    for (int r = 0; r < 256; ++r) acc += e2[q * 256 + r] * is2[r * 10 + C];
    M2[q * 10 + C] = acc;
}

// K4 v3: MFMA split-bf16 3-pass streaming GEMM.
//   v[b][n] = sum_k W[b][k] * e1[k][n],  W = p5[a]p6[a2]p9[c]p10[d], k=a.a2.c.d
// grid (64 kc, 4 ny); block 256 = 4 waves; wave = (mg = w>>1)x(ngr = w&1):
//   4 M-tiles (64 batches) x 2 N-tiles (32 cols), mfma_f32_16x16x32_bf16.
// A-fragments generated in registers from per-lane p9/p10/p5/p6 tables
// (rank-1 structure of W in k): no LDS, no barriers, fully unrolled stream.
// vpart layout identical to fp32 version (KC=64) -> k5 unchanged.
__global__ void __launch_bounds__(256, 1) k4_mfma(const float* __restrict__ e1,
                                                  const float* __restrict__ xv,
                                                  float* __restrict__ vpart) {
    int kc = blockIdx.x;        // 0..63  (1024 k's = 4 ab values)
    int ny = blockIdx.y;        // 0..3   (64-col slice)
    int tid = threadIdx.x;
    int wv = tid >> 6;          // wave 0..3
    int lane = tid & 63;
    int mg = wv >> 1;           // M-group (batches mg*64..mg*64+63)
    int ngr = wv & 1;           // N-group (32 cols)
    int l15 = lane & 15;
    int g = lane >> 4;          // k-group: A/B element k_loc = g*8+j
    int d0 = (g & 1) * 8;       // lane's fixed d-range within a 32-k step
    bool hic = (g & 2) != 0;    // lane's c-offset (0 or 1) within the step

    // per-lane tables (b = this lane's batch row per M-tile t)
    float p9r[4][16], p10r[4][8], p5r[4];
#pragma unroll
    for (int t = 0; t < 4; ++t) {
        int b = mg * 64 + t * 16 + l15;
        const float* xb = xv + b * 256;
#pragma unroll
        for (int c = 0; c < 16; ++c) p9r[t][c] = xb[144 + c];      // p9 row
#pragma unroll
        for (int j = 0; j < 8; ++j) p10r[t][j] = xb[160 + d0 + j]; // p10 half-row
        p5r[t] = xb[80 + (kc >> 2)];                               // a = kc>>2 fixed per block
    }

    int colbase = ny * 64 + ngr * 32;
    int col0 = colbase + l15;

    f32x4 acc[4][2];
#pragma unroll
    for (int t = 0; t < 4; ++t)
#pragma unroll
        for (int tn = 0; tn < 2; ++tn)
            acc[t][tn] = (f32x4){0.f, 0.f, 0.f, 0.f};

    const float* ep = e1 + ((size_t)(kc * 1024 + g * 8)) * 256;

    for (int abi = 0; abi < 4; ++abi) {          // runtime loop (4 ab's per chunk)
        int a2 = (kc & 3) * 4 + abi;             // p6 index for this ab
        float sab[4];
#pragma unroll
        for (int t = 0; t < 4; ++t) {
            int b = mg * 64 + t * 16 + l15;
            sab[t] = p5r[t] * xv[b * 256 + 96 + a2];
        }
#pragma unroll
        for (int cc = 0; cc < 8; ++cc) {         // 8 K-steps of 32 per ab
            // ---- B fragments: e1 rows kbase+g*8+j, cols col0 + tn*16 ----
            bf16x8 eh[2], el[2];
#pragma unroll
            for (int tn = 0; tn < 2; ++tn) {
                const float* ec = ep + (size_t)cc * 32 * 256 + col0 + tn * 16;
#pragma unroll
                for (int j = 0; j < 8; ++j) {
                    float evj = ec[(size_t)j * 256];
                    short h, l; splitf(evj, h, l);
                    eh[tn][j] = h; el[tn][j] = l;
                }
            }
            // ---- A fragments: W = sab * p9[c] * p10[d], c = 2cc + (g>>1) ----
            bf16x8 wh[4], wl[4];
#pragma unroll
            for (int t = 0; t < 4; ++t) {
                float s0 = sab[t] * p9r[t][2 * cc];
                float s1 = sab[t] * p9r[t][2 * cc + 1];
                float s = hic ? s1 : s0;
#pragma unroll
                for (int j = 0; j < 8; ++j) {
                    float wj = s * p10r[t][j];
                    short h, l; splitf(wj, h, l);
                    wh[t][j] = h; wl[t][j] = l;
                }
            }
            // ---- MFMA 3-pass: Wh*Eh + Wh*El + Wl*Eh ----
#pragma unroll
            for (int t = 0; t < 4; ++t)
#pragma unroll
                for (int tn = 0; tn < 2; ++tn) {
                    acc[t][tn] = __builtin_amdgcn_mfma_f32_16x16x32_bf16(wh[t], eh[tn], acc[t][tn], 0, 0, 0);
                    acc[t][tn] = __builtin_amdgcn_mfma_f32_16x16x32_bf16(wh[t], el[tn], acc[t][tn], 0, 0, 0);
                    acc[t][tn] = __builtin_amdgcn_mfma_f32_16x16x32_bf16(wl[t], eh[tn], acc[t][tn], 0, 0, 0);
                }
        }
        ep += (size_t)256 * 256;                 // advance 256 e1 rows per ab
    }

    // ---- store: D element (row = g*4 + r, col = l15) per tile ----
#pragma unroll
    for (int t = 0; t < 4; ++t) {
        int brow = mg * 64 + t * 16 + g * 4;
#pragma unroll
        for (int tn = 0; tn < 2; ++tn) {
            int col = colbase + tn * 16 + l15;
#pragma unroll
            for (int r = 0; r < 4; ++r) {
                vpart[((size_t)kc * 128 + brow + r) * 256 + col] = acc[t][tn][r];
            }
        }
    }
}

// K5: reduce split-K partials -> v[256]; then per-batch tail contraction.
__global__ void k5_final(const float* __restrict__ vpart, const float* __restrict__ tt,
                         const float* __restrict__ M2, const float* __restrict__ bias,
                         float* __restrict__ out) {
    __shared__ float v[256], A[256], Bb[256];
    __shared__ float t0[16], t1[16], t2[16], t3[16];
    int b = blockIdx.x, t = threadIdx.x;

    float4 s = make_float4(0.f, 0.f, 0.f, 0.f);
    for (int kc = 0; kc < KC; ++kc) {
        float4 pv = *(const float4*)&vpart[((size_t)kc * 128 + b) * 256 + t * 4];
        s.x += pv.x; s.y += pv.y; s.z += pv.z; s.w += pv.w;
    }
    *(float4*)&v[t * 4] = s;
    if (t < 16) {
        t0[t] = tt[0 * 2048 + b * 16 + t];
        t1[t] = tt[1 * 2048 + b * 16 + t];
        t2[t] = tt[2 * 2048 + b * 16 + t];
        t3[t] = tt[3 * 2048 + b * 16 + t];
    }
    __syncthreads();

    for (int q = 0; q < 4; ++q) {
        int idx = t * 4 + q;
        int a = idx >> 6, fgh = idx & 63;
        float acc = 0.f;
        for (int e = 0; e < 4; ++e) acc += t0[e * 4 + a] * v[e * 64 + fgh];
        A[idx] = acc;
    }
    __syncthreads();
    for (int q = 0; q < 4; ++q) {
        int idx = t * 4 + q;
        int a = idx >> 6, bb = (idx >> 4) & 3, gh = idx & 15;
        float acc = 0.f;
        for (int f = 0; f < 4; ++f) acc += t1[f * 4 + bb] * A[a * 64 + f * 16 + gh];
        Bb[idx] = acc;
    }
    __syncthreads();
    for (int q = 0; q < 4; ++q) {
        int idx = t * 4 + q;
        int ab = idx >> 4, c = (idx >> 2) & 3, h = idx & 3;
        float acc = 0.f;
        for (int g = 0; g < 4; ++g) acc += t2[g * 4 + c] * Bb[ab * 16 + g * 4 + h];
        A[idx] = acc;
    }
    __syncthreads();
    for (int q = 0; q < 4; ++q) {
        int idx = t * 4 + q;
        int abc = idx >> 2, dd = idx & 3;
        float acc = 0.f;
        for (int h = 0; h < 4; ++h) acc += t3[h * 4 + dd] * A[abc * 4 + h];
        Bb[idx] = acc;
    }
    __syncthreads();
    if (t < 10) {
        float acc = bias[t];
        for (int q = 0; q < 256; ++q) acc += Bb[q] * M2[q * 10 + t];
        out[b * 10 + t] = acc;
    }
}

extern "C" void kernel_launch(void* const* d_in, const int* in_sizes, int n_in,
                              void* d_out, int out_size, void* d_ws, size_t ws_size,
                              hipStream_t stream) {
    const float* in    = (const float*)d_in[0];
    const float* e1    = (const float*)d_in[1];
    const float* e2    = (const float*)d_in[2];
    const float* iso10 = (const float*)d_in[3];
    const float* iso11 = (const float*)d_in[4];
    const float* iso12 = (const float*)d_in[5];
    const float* iso13 = (const float*)d_in[6];
    const float* iso2  = (const float*)d_in[7];
    const float* bias  = (const float*)d_in[8];
    float* out = (float*)d_out;

    char* ws = (char*)d_ws;
    float* xv    = (float*)(ws + 0);
    float* tt    = (float*)(ws + 131072);
    float* M2    = (float*)(ws + 163840);
    float* vpart = (float*)(ws + 262144);

    hipLaunchKernelGGL(k1_xv, dim3(128), dim3(256), 0, stream, in, xv);
    hipLaunchKernelGGL(k2_iso, dim3(128, 4), dim3(256), 0, stream,
                       iso10, iso11, iso12, iso13, xv, tt);
    hipLaunchKernelGGL(k3_m2, dim3(10), dim3(256), 0, stream, e2, iso2, M2);
    hipLaunchKernelGGL(k4_mfma, dim3(KC, 4), dim3(256), 0, stream, e1, xv, vpart);
    hipLaunchKernelGGL(k5_final, dim3(128), dim3(64), 0, stream,
                       vpart, tt, M2, bias, out);
}